// Round 22
// baseline (553.328 us; speedup 1.0000x reference)
//
#include <hip/hip_runtime.h>
#include <hip/hip_bf16.h>
#include <math.h>

#define NB 4
#define NPI 12000
#define NM 32
#define NPTS (NB*NPI*NM)      // 1536000
#define NPIL (NB*NPI)         // 48000

// k_moments config
#define K1_BLOCKS 1500
#define K1_STRIDE (K1_BLOCKS*256)   // 384000
#define K1_ITERS 4                  // NPTS / K1_STRIDE
#define NMOM 54                     // 9 Sf + 45 Sff

// heavy-kernel config
#define CHUNK 128
#define NBATCH (NPTS/CHUNK)   // 12000
#define SB 1024               // 4 blocks/CU x 256 CU resident (LDS 32KB)

typedef __attribute__((ext_vector_type(8))) short bfrag;     // 8 bf16 = 4 VGPRs
typedef __attribute__((ext_vector_type(16))) float f32x16;   // MFMA 32x32 acc

// ---------------------------------------------------------------- helpers

__device__ __forceinline__ void make_f(float4 v, int4 cc, int np, int m, float zc, float f[9]) {
  const float cx = ((float)cc.w + 0.5f) * 0.16f + 0.0f;
  const float cy = ((float)cc.z + 0.5f) * 0.16f - 39.68f;
  f[0] = v.x; f[1] = v.y; f[2] = v.z; f[3] = v.w;
  f[4] = v.x - cx; f[5] = v.y - cy; f[6] = cx; f[7] = cy; f[8] = zc;
  const float msk = (m < np) ? 1.0f : 0.0f;
#pragma unroll
  for (int i = 0; i < 9; ++i) f[i] *= msk;
}

// ------------------------------------------------- K1: f-moments + last-block fin1
// R21 post-mortem: cooperative launch silently failed (out stayed zero) ->
// fuse reduces/finalizes via the standard last-block pattern instead:
// every block writes partials, fences, bumps a device-scope counter; the
// single block seeing count==K1_BLOCKS-1 does the fixed-order f64 reduction
// + fin1 (deterministic). Counter zeroed per-call by a captured memset.

__global__ __launch_bounds__(256) void k_moments(
    const float4* __restrict__ vox, const int4* __restrict__ coords,
    const int* __restrict__ npnts, const float* __restrict__ W1,
    const float* __restrict__ g1, const float* __restrict__ b1,
    float* __restrict__ P1, float* __restrict__ params,
    int* __restrict__ cnt) {
  const int t = threadIdx.x;
  const int wave = t >> 6, lane = t & 63;
  float acc[NMOM];
#pragma unroll
  for (int v = 0; v < NMOM; ++v) acc[v] = 0.0f;

  const int base = blockIdx.x * 256 + t;
#pragma unroll
  for (int j = 0; j < K1_ITERS; ++j) {
    const int pt = base + j * K1_STRIDE;
    const int pil = pt >> 5;
    const int m = pt & 31;
    const float4 v = vox[pt];
    const int4 cc = coords[pil];
    const int np = npnts[pil];
    float z = v.z;
#pragma unroll
    for (int s = 1; s < 32; s <<= 1) z += __shfl_xor(z, s, 32);
    const float zc = z * (1.0f / 32.0f);
    float f[9];
    make_f(v, cc, np, m, zc, f);
    int vi = 0;
#pragma unroll
    for (int i = 0; i < 9; ++i) acc[vi++] += f[i];
#pragma unroll
    for (int i = 0; i < 9; ++i)
#pragma unroll
      for (int jj = i; jj < 9; ++jj) acc[vi++] += f[i] * f[jj];
  }

#pragma unroll
  for (int v = 0; v < NMOM; ++v) {
    float x = acc[v];
#pragma unroll
    for (int s = 1; s < 64; s <<= 1) x += __shfl_xor(x, s, 64);
    acc[v] = x;
  }
  __shared__ float red[4][NMOM];
  if (lane == 0) {
#pragma unroll
    for (int v = 0; v < NMOM; ++v) red[wave][v] = acc[v];
  }
  __syncthreads();
  if (t < NMOM) {
    P1[t * K1_BLOCKS + blockIdx.x] =
        red[0][t] + red[1][t] + red[2][t] + red[3][t];
  }

  // ---- last-block T1 reduce + fin1
  __shared__ int lastflag;
  __threadfence();
  __syncthreads();
  if (t == 0) lastflag = (atomicAdd(cnt, 1) == K1_BLOCKS - 1) ? 1 : 0;
  __syncthreads();
  if (!lastflag) return;

  __shared__ double T1d[NMOM];
  for (int r = wave; r < NMOM; r += 4) {
    double sd = 0.0;
    for (int k = lane; k < K1_BLOCKS; k += 64) sd += (double)P1[r * K1_BLOCKS + k];
#pragma unroll
    for (int s = 1; s < 64; s <<= 1) sd += __shfl_xor(sd, s, 64);
    if (lane == 0) T1d[r] = sd;
  }
  __syncthreads();
  if (t < 64) {
    double w[9];
#pragma unroll
    for (int i = 0; i < 9; ++i) w[i] = (double)W1[i * 64 + t];
    double mean = 0.0;
#pragma unroll
    for (int i = 0; i < 9; ++i) mean += w[i] * T1d[i];
    mean /= (double)NPTS;
    double e2 = 0.0;
    int vi = 9;
#pragma unroll
    for (int i = 0; i < 9; ++i)
#pragma unroll
      for (int j = i; j < 9; ++j) {
        const double tt = T1d[vi++] * w[i] * w[j];
        e2 += (i == j) ? tt : 2.0 * tt;
      }
    e2 /= (double)NPTS;
    const double var = e2 - mean * mean;
    const double a = (double)g1[t] / sqrt(var + 0.001);
    params[t] = (float)a;
    params[64 + t] = (float)((double)b1[t] - mean * a);
  }
}

// ------------------------------------------------- K3: both layers via MFMA (R20)
// + last-block T2 reduce + fin2 (same decoupled pattern).

__global__ __launch_bounds__(256) void k_stats2(
    const float4* __restrict__ vox, const int4* __restrict__ coords,
    const int* __restrict__ npnts, const float* __restrict__ W1,
    const float* __restrict__ W2, const float* __restrict__ g2,
    const float* __restrict__ b2, float* __restrict__ params,
    float* __restrict__ P2, float* __restrict__ Y2SEL,
    int* __restrict__ cnt2) {
  __shared__ __align__(16) unsigned int smem[8192];   // 32768 B total
  unsigned short* h1 = (unsigned short*)smem;                // [128][64] u16 (swz)
  unsigned short* W2T = (unsigned short*)(smem + 4096);      // [64][128] u16 interleaved (swz)
  // init-only aliases inside the h1 region (dead after reg-hoist + barrier):
  unsigned short* W1Thi = (unsigned short*)smem;             // [64][16]
  unsigned short* W1Tlo = (unsigned short*)(smem + 512);     // [64][16]

  const int t = threadIdx.x;
  // stage W1aug^T split (k padded 10->16): k<9: W1[k][c]*a1[c]; k==9: b1adj[c]
  for (int i = t; i < 1024; i += 256) {
    const int c = i >> 4, k = i & 15;
    float x;
    if (k < 9)       x = W1[k * 64 + c] * params[c];
    else if (k == 9) x = params[64 + c];
    else             x = 0.0f;
    const unsigned int b = __float_as_uint(x);
    W1Thi[c * 16 + k] = (unsigned short)(b >> 16);
    const float r = x - __uint_as_float(b & 0xFFFF0000u);
    W1Tlo[c * 16 + k] = (unsigned short)(__float_as_uint(r) >> 16);
  }
  // stage W2^T split, interleaved+swizzled: hi(ch,k) at col k^sw, lo at (64+k)^sw
  for (int i = t; i < 4096; i += 256) {
    const int k = i >> 6, c = i & 63;
    const float x = W2[i];
    const unsigned int b = __float_as_uint(x);
    const float r = x - __uint_as_float(b & 0xFFFF0000u);
    const int sw = (c & 15) << 3;
    W2T[c * 128 + (k ^ sw)] = (unsigned short)(b >> 16);
    W2T[c * 128 + ((64 + k) ^ sw)] = (unsigned short)(__float_as_uint(r) >> 16);
  }

  const int lane = t & 63;
  const int wv = t >> 6;                      // wave owns pillar wv of each batch
  const int ch = lane & 31;                   // tile-local channel / point id
  const float sg0 = (g2[ch] >= 0.0f) ? 1.0f : -1.0f;
  const float sg1 = (g2[32 + ch] >= 0.0f) ? 1.0f : -1.0f;
  __syncthreads();   // staging visible to all waves

  const int koff = 8 * (lane >> 5);           // k base within 16-wide step
  const int arow = 32 * wv + ch;              // A row (= this lane's point)
  const int swB = (ch & 15) << 3;             // W2T read swizzle (u16 units)
  const int swA = (arow & 7) << 3;            // h1 read swizzle (u16 units)
  const bfrag w1h0 = *(const bfrag*)&W1Thi[ch * 16 + koff];
  const bfrag w1l0 = *(const bfrag*)&W1Tlo[ch * 16 + koff];
  const bfrag w1h1 = *(const bfrag*)&W1Thi[(32 + ch) * 16 + koff];
  const bfrag w1l1 = *(const bfrag*)&W1Tlo[(32 + ch) * 16 + koff];
  __syncthreads();   // ALL waves done reading W1T staging before h1 overwrite

  f32x16 zero16;
#pragma unroll
  for (int i = 0; i < 16; ++i) zero16[i] = 0.0f;

  float psum = 0.0f, psq = 0.0f;

  int bb0 = blockIdx.x;
  float4 v = vox[bb0 * CHUNK + 32 * wv + ch];
  int4 cc = coords[bb0 * 4 + wv];
  int np = npnts[bb0 * 4 + wv];

  for (int bb = bb0; bb < NBATCH; bb += SB) {
    float z = v.z;
#pragma unroll
    for (int s = 1; s < 64; s <<= 1) z += __shfl_xor(z, s, 64);
    const float zc = z * (1.0f / 64.0f);
    float f[9];
    make_f(v, cc, np, ch, zc, f);
    {
      const int bbn = bb + SB;
      const int bbs = (bbn < NBATCH) ? bbn : bb;
      v = vox[bbs * CHUNK + 32 * wv + ch];
      cc = coords[bbs * 4 + wv];
      np = npnts[bbs * 4 + wv];
    }
    bfrag fa_hi, fa_lo;
    {
      unsigned int ahw[4] = {0u, 0u, 0u, 0u}, alw[4] = {0u, 0u, 0u, 0u};
#pragma unroll
      for (int e = 0; e < 8; ++e) {
        const float x = (lane < 32) ? f[e]
                        : ((e == 0) ? f[8] : (e == 1) ? 1.0f : 0.0f);
        const unsigned int b = __float_as_uint(x);
        const float r = x - __uint_as_float(b & 0xFFFF0000u);
        ahw[e >> 1] |= (b >> 16) << ((e & 1) * 16);
        alw[e >> 1] |= (__float_as_uint(r) >> 16) << ((e & 1) * 16);
      }
      union U { unsigned int u[4]; bfrag b; };
      U ch_, cl_;
      ch_.u[0] = ahw[0]; ch_.u[1] = ahw[1]; ch_.u[2] = ahw[2]; ch_.u[3] = ahw[3];
      cl_.u[0] = alw[0]; cl_.u[1] = alw[1]; cl_.u[2] = alw[2]; cl_.u[3] = alw[3];
      fa_hi = ch_.b; fa_lo = cl_.b;
    }

    f32x16 yA0 = __builtin_amdgcn_mfma_f32_32x32x16_bf16(fa_hi, w1h0, zero16, 0, 0, 0);
    f32x16 yA1 = __builtin_amdgcn_mfma_f32_32x32x16_bf16(fa_hi, w1h1, zero16, 0, 0, 0);
    yA0 = __builtin_amdgcn_mfma_f32_32x32x16_bf16(fa_hi, w1l0, yA0, 0, 0, 0);
    yA1 = __builtin_amdgcn_mfma_f32_32x32x16_bf16(fa_hi, w1l1, yA1, 0, 0, 0);
    yA0 = __builtin_amdgcn_mfma_f32_32x32x16_bf16(fa_lo, w1h0, yA0, 0, 0, 0);
    yA1 = __builtin_amdgcn_mfma_f32_32x32x16_bf16(fa_lo, w1h1, yA1, 0, 0, 0);

    const int rbase = 4 * (lane >> 5);
#pragma unroll
    for (int j = 0; j < 4; ++j) {
      const int swzj = ((j + rbase) & 7) << 3;   // u16 units
      unsigned short* bp0 = &h1[(32 * wv + rbase + j) * 64 + (ch ^ swzj)];
      unsigned short* bp1 = &h1[(32 * wv + rbase + j) * 64 + ((32 + ch) ^ swzj)];
#pragma unroll
      for (int q = 0; q < 4; ++q) {
        const int reg = j + 4 * q;
        {
          const __hip_bfloat16 hb = __float2bfloat16(fmaxf(yA0[reg], 0.0f));
          bp0[q * 512] = *(const unsigned short*)&hb;
        }
        {
          const __hip_bfloat16 hb = __float2bfloat16(fmaxf(yA1[reg], 0.0f));
          bp1[q * 512] = *(const unsigned short*)&hb;
        }
      }
    }
    // no barrier: wave-private rows (within-wave DS ordering)

    f32x16 acc0, acc1;
#pragma unroll
    for (int ks = 0; ks < 4; ++ks) {
      const int kk = koff + 16 * ks;
      const bfrag ahi = *(const bfrag*)&h1[arow * 64 + (kk ^ swA)];
      const bfrag bhi0 = *(const bfrag*)&W2T[ch * 128 + (kk ^ swB)];
      const bfrag blo0 = *(const bfrag*)&W2T[ch * 128 + ((64 + kk) ^ swB)];
      const bfrag bhi1 = *(const bfrag*)&W2T[(32 + ch) * 128 + (kk ^ swB)];
      const bfrag blo1 = *(const bfrag*)&W2T[(32 + ch) * 128 + ((64 + kk) ^ swB)];
      if (ks == 0) {
        acc0 = __builtin_amdgcn_mfma_f32_32x32x16_bf16(ahi, bhi0, zero16, 0, 0, 0);
        acc1 = __builtin_amdgcn_mfma_f32_32x32x16_bf16(ahi, bhi1, zero16, 0, 0, 0);
      } else {
        acc0 = __builtin_amdgcn_mfma_f32_32x32x16_bf16(ahi, bhi0, acc0, 0, 0, 0);
        acc1 = __builtin_amdgcn_mfma_f32_32x32x16_bf16(ahi, bhi1, acc1, 0, 0, 0);
      }
      acc0 = __builtin_amdgcn_mfma_f32_32x32x16_bf16(ahi, blo0, acc0, 0, 0, 0);
      acc1 = __builtin_amdgcn_mfma_f32_32x32x16_bf16(ahi, blo1, acc1, 0, 0, 0);
    }

    float s0 = 0, q0 = 0, m0 = -INFINITY, s1 = 0, q1 = 0, m1 = -INFINITY;
#pragma unroll
    for (int i = 0; i < 16; ++i) {
      const float v0 = acc0[i], v1 = acc1[i];
      s0 += v0; q0 = fmaf(v0, v0, q0); m0 = fmaxf(m0, v0 * sg0);
      s1 += v1; q1 = fmaf(v1, v1, q1); m1 = fmaxf(m1, v1 * sg1);
    }
    s0 += __shfl_xor(s0, 32, 64); q0 += __shfl_xor(q0, 32, 64);
    m0 = fmaxf(m0, __shfl_xor(m0, 32, 64));
    s1 += __shfl_xor(s1, 32, 64); q1 += __shfl_xor(q1, 32, 64);
    m1 = fmaxf(m1, __shfl_xor(m1, 32, 64));
    const bool hiHalf = lane >= 32;   // lane's own channel = lane
    psum += hiHalf ? s1 : s0;
    psq += hiHalf ? q1 : q0;
    Y2SEL[(bb * 4 + wv) * 64 + lane] = hiHalf ? m1 : m0;   // coalesced
  }

  // block reduction -> P2 partials (alias smem, barrier-separated)
  __syncthreads();
  {
    float* redS = (float*)smem;           // 256 floats
    float* redQ = (float*)(smem + 256);   // 256 floats
    redS[wv * 64 + lane] = psum;
    redQ[wv * 64 + lane] = psq;
    __syncthreads();
    if (t < 64) {
      const float s = redS[t] + redS[64 + t] + redS[128 + t] + redS[192 + t];
      const float q = redQ[t] + redQ[64 + t] + redQ[128 + t] + redQ[192 + t];
      P2[t * SB + blockIdx.x] = s;
      P2[(64 + t) * SB + blockIdx.x] = q;
    }
  }

  // ---- last-block T2 reduce + fin2
  __shared__ int lastflag;
  __threadfence();
  __syncthreads();
  if (t == 0) lastflag = (atomicAdd(cnt2, 1) == SB - 1) ? 1 : 0;
  __syncthreads();
  if (!lastflag) return;

  double* T2d = (double*)smem;   // 128 f64 (1KB; smem dead post-loop)
  for (int r = wv; r < 128; r += 4) {
    double sd = 0.0;
    for (int k = lane; k < SB; k += 64) sd += (double)P2[r * SB + k];
#pragma unroll
    for (int s = 1; s < 64; s <<= 1) sd += __shfl_xor(sd, s, 64);
    if (lane == 0) T2d[r] = sd;
  }
  __syncthreads();
  if (t < 64) {
    const double mean = T2d[t] / (double)NPTS;
    const double var = T2d[64 + t] / (double)NPTS - mean * mean;
    const double a = (double)g2[t] / sqrt(var + 0.001);
    params[128 + t] = (float)a;
    params[192 + t] = (float)((double)b2[t] - mean * a);
  }
}

// ------------------------------------------------- K5: final output pass.

__global__ __launch_bounds__(256) void k_final(
    const float* __restrict__ params, const float* __restrict__ Y2SEL,
    float* __restrict__ out) {
  const int idx = blockIdx.x * 256 + threadIdx.x;   // NPIL*64 total
  const int c = idx & 63;
  const float a2 = params[128 + c];
  const float b2 = params[192 + c];
  const float v = Y2SEL[idx];
  const float sel = (a2 >= 0.0f) ? v : -v;
  out[idx] = fmaxf(fmaf(sel, a2, b2), 0.0f);
}

// ---------------------------------------------------------------- launch

extern "C" void kernel_launch(void* const* d_in, const int* in_sizes, int n_in,
                              void* d_out, int out_size, void* d_ws, size_t ws_size,
                              hipStream_t stream) {
  const float4* vox = (const float4*)d_in[0];
  const int4* coords = (const int4*)d_in[1];
  const int* npnts = (const int*)d_in[2];
  const float* W1 = (const float*)d_in[3];
  const float* g1 = (const float*)d_in[4];
  const float* b1 = (const float*)d_in[5];
  const float* W2 = (const float*)d_in[6];
  const float* g2 = (const float*)d_in[7];
  const float* b2 = (const float*)d_in[8];
  float* out = (float*)d_out;

  char* w = (char*)d_ws;
  size_t off = 0;
  int* counters = (int*)(w + off); off += 256;                     // 2 used
  float* P1 = (float*)(w + off); off += (size_t)NMOM * K1_BLOCKS * 4;  // 324 KB
  float* P2 = (float*)(w + off); off += (size_t)128 * SB * 4;      // 524 KB
  float* params = (float*)(w + off); off += 256 * 4;               // 256 f32
  float* Y2SEL = (float*)(w + off); off += (size_t)NPIL * 64 * 4;  // 12.3 MB

  // zero the last-block counters (captured into the graph; runs every replay)
  hipMemsetAsync(counters, 0, 8, stream);
  k_moments<<<K1_BLOCKS, 256, 0, stream>>>(vox, coords, npnts, W1, g1, b1,
                                           P1, params, &counters[0]);
  k_stats2<<<SB, 256, 0, stream>>>(vox, coords, npnts, W1, W2, g2, b2,
                                   params, P2, Y2SEL, &counters[1]);
  k_final<<<(NPIL * 64) / 256, 256, 0, stream>>>(params, Y2SEL, out);
}

// Round 23
// 345.537 us; speedup vs baseline: 1.6014x; 1.6014x over previous
//
#include <hip/hip_runtime.h>
#include <hip/hip_bf16.h>
#include <math.h>

#define NB 4
#define NPI 12000
#define NM 32
#define NPTS (NB*NPI*NM)      // 1536000
#define NPIL (NB*NPI)         // 48000

// k_moments config
#define K1_BLOCKS 1500
#define K1_STRIDE (K1_BLOCKS*256)   // 384000
#define K1_ITERS 4                  // NPTS / K1_STRIDE
#define NMOM 54                     // 9 Sf + 45 Sff

// heavy-kernel config
#define CHUNK 128
#define NBATCH (NPTS/CHUNK)   // 12000
#define SB 1024               // 4 blocks/CU x 256 CU resident (LDS 32KB)

typedef __attribute__((ext_vector_type(8))) short bfrag;     // 8 bf16 = 4 VGPRs
typedef __attribute__((ext_vector_type(16))) float f32x16;   // MFMA 32x32 acc

// ---------------------------------------------------------------- helpers

__device__ __forceinline__ void make_f(float4 v, int4 cc, int np, int m, float zc, float f[9]) {
  const float cx = ((float)cc.w + 0.5f) * 0.16f + 0.0f;
  const float cy = ((float)cc.z + 0.5f) * 0.16f - 39.68f;
  f[0] = v.x; f[1] = v.y; f[2] = v.z; f[3] = v.w;
  f[4] = v.x - cx; f[5] = v.y - cy; f[6] = cx; f[7] = cy; f[8] = zc;
  const float msk = (m < np) ? 1.0f : 0.0f;
#pragma unroll
  for (int i = 0; i < 9; ++i) f[i] *= msk;
}

// ------------------------------------------------- K1: f-moments (R20 exact)

__global__ __launch_bounds__(256) void k_moments(
    const float4* __restrict__ vox, const int4* __restrict__ coords,
    const int* __restrict__ npnts, float* __restrict__ P1) {
  const int t = blockIdx.x * 256 + threadIdx.x;
  float acc[NMOM];
#pragma unroll
  for (int v = 0; v < NMOM; ++v) acc[v] = 0.0f;

#pragma unroll
  for (int j = 0; j < K1_ITERS; ++j) {
    const int pt = t + j * K1_STRIDE;
    const int pil = pt >> 5;
    const int m = pt & 31;
    const float4 v = vox[pt];
    const int4 cc = coords[pil];
    const int np = npnts[pil];
    float z = v.z;
#pragma unroll
    for (int s = 1; s < 32; s <<= 1) z += __shfl_xor(z, s, 32);
    const float zc = z * (1.0f / 32.0f);
    float f[9];
    make_f(v, cc, np, m, zc, f);
    int vi = 0;
#pragma unroll
    for (int i = 0; i < 9; ++i) acc[vi++] += f[i];
#pragma unroll
    for (int i = 0; i < 9; ++i)
#pragma unroll
      for (int jj = i; jj < 9; ++jj) acc[vi++] += f[i] * f[jj];
  }

#pragma unroll
  for (int v = 0; v < NMOM; ++v) {
    float x = acc[v];
#pragma unroll
    for (int s = 1; s < 64; s <<= 1) x += __shfl_xor(x, s, 64);
    acc[v] = x;
  }
  __shared__ float red[4][NMOM];
  const int wave = threadIdx.x >> 6, lane = threadIdx.x & 63;
  if (lane == 0) {
#pragma unroll
    for (int v = 0; v < NMOM; ++v) red[wave][v] = acc[v];
  }
  __syncthreads();
  if (threadIdx.x < NMOM) {
    float s = red[0][threadIdx.x] + red[1][threadIdx.x] + red[2][threadIdx.x] + red[3][threadIdx.x];
    P1[threadIdx.x * K1_BLOCKS + blockIdx.x] = s;
  }
}

// ------------------------------------------------- k_red1: T1 reduce + fin1
// Single block (no atomics/fences -- R21/R22 lesson). 4 waves, lane-strided
// f64 sums + butterfly, fixed order -> deterministic.

__global__ __launch_bounds__(256) void k_red1(
    const float* __restrict__ P1, const float* __restrict__ W1,
    const float* __restrict__ g1, const float* __restrict__ b1,
    float* __restrict__ params) {
  const int t = threadIdx.x;
  const int wave = t >> 6, lane = t & 63;
  __shared__ double T1d[NMOM];
  for (int r = wave; r < NMOM; r += 4) {
    double sd = 0.0;
    for (int k = lane; k < K1_BLOCKS; k += 64) sd += (double)P1[r * K1_BLOCKS + k];
#pragma unroll
    for (int s = 1; s < 64; s <<= 1) sd += __shfl_xor(sd, s, 64);
    if (lane == 0) T1d[r] = sd;
  }
  __syncthreads();
  if (t < 64) {
    double w[9];
#pragma unroll
    for (int i = 0; i < 9; ++i) w[i] = (double)W1[i * 64 + t];
    double mean = 0.0;
#pragma unroll
    for (int i = 0; i < 9; ++i) mean += w[i] * T1d[i];
    mean /= (double)NPTS;
    double e2 = 0.0;
    int vi = 9;
#pragma unroll
    for (int i = 0; i < 9; ++i)
#pragma unroll
      for (int j = i; j < 9; ++j) {
        const double tt = T1d[vi++] * w[i] * w[j];
        e2 += (i == j) ? tt : 2.0 * tt;
      }
    e2 /= (double)NPTS;
    const double var = e2 - mean * mean;
    const double a = (double)g1[t] / sqrt(var + 0.001);
    params[t] = (float)a;
    params[64 + t] = (float)((double)b1[t] - mean * a);
  }
}

// ------------------------------------------------- K3: both layers via MFMA (R20 exact)

__global__ __launch_bounds__(256) void k_stats2(
    const float4* __restrict__ vox, const int4* __restrict__ coords,
    const int* __restrict__ npnts, const float* __restrict__ W1,
    const float* __restrict__ W2, const float* __restrict__ g2,
    const float* __restrict__ params, float* __restrict__ P2,
    float* __restrict__ Y2SEL) {
  __shared__ __align__(16) unsigned int smem[8192];   // 32768 B total
  unsigned short* h1 = (unsigned short*)smem;                // [128][64] u16 (swz)
  unsigned short* W2T = (unsigned short*)(smem + 4096);      // [64][128] u16 interleaved (swz)
  unsigned short* W1Thi = (unsigned short*)smem;             // [64][16] (init-only alias)
  unsigned short* W1Tlo = (unsigned short*)(smem + 512);     // [64][16]

  const int t = threadIdx.x;
  for (int i = t; i < 1024; i += 256) {
    const int c = i >> 4, k = i & 15;
    float x;
    if (k < 9)       x = W1[k * 64 + c] * params[c];
    else if (k == 9) x = params[64 + c];
    else             x = 0.0f;
    const unsigned int b = __float_as_uint(x);
    W1Thi[c * 16 + k] = (unsigned short)(b >> 16);
    const float r = x - __uint_as_float(b & 0xFFFF0000u);
    W1Tlo[c * 16 + k] = (unsigned short)(__float_as_uint(r) >> 16);
  }
  for (int i = t; i < 4096; i += 256) {
    const int k = i >> 6, c = i & 63;
    const float x = W2[i];
    const unsigned int b = __float_as_uint(x);
    const float r = x - __uint_as_float(b & 0xFFFF0000u);
    const int sw = (c & 15) << 3;
    W2T[c * 128 + (k ^ sw)] = (unsigned short)(b >> 16);
    W2T[c * 128 + ((64 + k) ^ sw)] = (unsigned short)(__float_as_uint(r) >> 16);
  }

  const int lane = t & 63;
  const int wv = t >> 6;
  const int ch = lane & 31;
  const float sg0 = (g2[ch] >= 0.0f) ? 1.0f : -1.0f;
  const float sg1 = (g2[32 + ch] >= 0.0f) ? 1.0f : -1.0f;
  __syncthreads();

  const int koff = 8 * (lane >> 5);
  const int arow = 32 * wv + ch;
  const int swB = (ch & 15) << 3;
  const int swA = (arow & 7) << 3;
  const bfrag w1h0 = *(const bfrag*)&W1Thi[ch * 16 + koff];
  const bfrag w1l0 = *(const bfrag*)&W1Tlo[ch * 16 + koff];
  const bfrag w1h1 = *(const bfrag*)&W1Thi[(32 + ch) * 16 + koff];
  const bfrag w1l1 = *(const bfrag*)&W1Tlo[(32 + ch) * 16 + koff];
  __syncthreads();

  f32x16 zero16;
#pragma unroll
  for (int i = 0; i < 16; ++i) zero16[i] = 0.0f;

  float psum = 0.0f, psq = 0.0f;

  int bb0 = blockIdx.x;
  float4 v = vox[bb0 * CHUNK + 32 * wv + ch];
  int4 cc = coords[bb0 * 4 + wv];
  int np = npnts[bb0 * 4 + wv];

  for (int bb = bb0; bb < NBATCH; bb += SB) {
    float z = v.z;
#pragma unroll
    for (int s = 1; s < 64; s <<= 1) z += __shfl_xor(z, s, 64);
    const float zc = z * (1.0f / 64.0f);
    float f[9];
    make_f(v, cc, np, ch, zc, f);
    {
      const int bbn = bb + SB;
      const int bbs = (bbn < NBATCH) ? bbn : bb;
      v = vox[bbs * CHUNK + 32 * wv + ch];
      cc = coords[bbs * 4 + wv];
      np = npnts[bbs * 4 + wv];
    }
    bfrag fa_hi, fa_lo;
    {
      unsigned int ahw[4] = {0u, 0u, 0u, 0u}, alw[4] = {0u, 0u, 0u, 0u};
#pragma unroll
      for (int e = 0; e < 8; ++e) {
        const float x = (lane < 32) ? f[e]
                        : ((e == 0) ? f[8] : (e == 1) ? 1.0f : 0.0f);
        const unsigned int b = __float_as_uint(x);
        const float r = x - __uint_as_float(b & 0xFFFF0000u);
        ahw[e >> 1] |= (b >> 16) << ((e & 1) * 16);
        alw[e >> 1] |= (__float_as_uint(r) >> 16) << ((e & 1) * 16);
      }
      union U { unsigned int u[4]; bfrag b; };
      U ch_, cl_;
      ch_.u[0] = ahw[0]; ch_.u[1] = ahw[1]; ch_.u[2] = ahw[2]; ch_.u[3] = ahw[3];
      cl_.u[0] = alw[0]; cl_.u[1] = alw[1]; cl_.u[2] = alw[2]; cl_.u[3] = alw[3];
      fa_hi = ch_.b; fa_lo = cl_.b;
    }

    f32x16 yA0 = __builtin_amdgcn_mfma_f32_32x32x16_bf16(fa_hi, w1h0, zero16, 0, 0, 0);
    f32x16 yA1 = __builtin_amdgcn_mfma_f32_32x32x16_bf16(fa_hi, w1h1, zero16, 0, 0, 0);
    yA0 = __builtin_amdgcn_mfma_f32_32x32x16_bf16(fa_hi, w1l0, yA0, 0, 0, 0);
    yA1 = __builtin_amdgcn_mfma_f32_32x32x16_bf16(fa_hi, w1l1, yA1, 0, 0, 0);
    yA0 = __builtin_amdgcn_mfma_f32_32x32x16_bf16(fa_lo, w1h0, yA0, 0, 0, 0);
    yA1 = __builtin_amdgcn_mfma_f32_32x32x16_bf16(fa_lo, w1h1, yA1, 0, 0, 0);

    const int rbase = 4 * (lane >> 5);
#pragma unroll
    for (int j = 0; j < 4; ++j) {
      const int swzj = ((j + rbase) & 7) << 3;
      unsigned short* bp0 = &h1[(32 * wv + rbase + j) * 64 + (ch ^ swzj)];
      unsigned short* bp1 = &h1[(32 * wv + rbase + j) * 64 + ((32 + ch) ^ swzj)];
#pragma unroll
      for (int q = 0; q < 4; ++q) {
        const int reg = j + 4 * q;
        {
          const __hip_bfloat16 hb = __float2bfloat16(fmaxf(yA0[reg], 0.0f));
          bp0[q * 512] = *(const unsigned short*)&hb;
        }
        {
          const __hip_bfloat16 hb = __float2bfloat16(fmaxf(yA1[reg], 0.0f));
          bp1[q * 512] = *(const unsigned short*)&hb;
        }
      }
    }
    // no barrier: wave-private rows (within-wave DS ordering)

    f32x16 acc0, acc1;
#pragma unroll
    for (int ks = 0; ks < 4; ++ks) {
      const int kk = koff + 16 * ks;
      const bfrag ahi = *(const bfrag*)&h1[arow * 64 + (kk ^ swA)];
      const bfrag bhi0 = *(const bfrag*)&W2T[ch * 128 + (kk ^ swB)];
      const bfrag blo0 = *(const bfrag*)&W2T[ch * 128 + ((64 + kk) ^ swB)];
      const bfrag bhi1 = *(const bfrag*)&W2T[(32 + ch) * 128 + (kk ^ swB)];
      const bfrag blo1 = *(const bfrag*)&W2T[(32 + ch) * 128 + ((64 + kk) ^ swB)];
      if (ks == 0) {
        acc0 = __builtin_amdgcn_mfma_f32_32x32x16_bf16(ahi, bhi0, zero16, 0, 0, 0);
        acc1 = __builtin_amdgcn_mfma_f32_32x32x16_bf16(ahi, bhi1, zero16, 0, 0, 0);
      } else {
        acc0 = __builtin_amdgcn_mfma_f32_32x32x16_bf16(ahi, bhi0, acc0, 0, 0, 0);
        acc1 = __builtin_amdgcn_mfma_f32_32x32x16_bf16(ahi, bhi1, acc1, 0, 0, 0);
      }
      acc0 = __builtin_amdgcn_mfma_f32_32x32x16_bf16(ahi, blo0, acc0, 0, 0, 0);
      acc1 = __builtin_amdgcn_mfma_f32_32x32x16_bf16(ahi, blo1, acc1, 0, 0, 0);
    }

    float s0 = 0, q0 = 0, m0 = -INFINITY, s1 = 0, q1 = 0, m1 = -INFINITY;
#pragma unroll
    for (int i = 0; i < 16; ++i) {
      const float v0 = acc0[i], v1 = acc1[i];
      s0 += v0; q0 = fmaf(v0, v0, q0); m0 = fmaxf(m0, v0 * sg0);
      s1 += v1; q1 = fmaf(v1, v1, q1); m1 = fmaxf(m1, v1 * sg1);
    }
    s0 += __shfl_xor(s0, 32, 64); q0 += __shfl_xor(q0, 32, 64);
    m0 = fmaxf(m0, __shfl_xor(m0, 32, 64));
    s1 += __shfl_xor(s1, 32, 64); q1 += __shfl_xor(q1, 32, 64);
    m1 = fmaxf(m1, __shfl_xor(m1, 32, 64));
    const bool hiHalf = lane >= 32;
    psum += hiHalf ? s1 : s0;
    psq += hiHalf ? q1 : q0;
    Y2SEL[(bb * 4 + wv) * 64 + lane] = hiHalf ? m1 : m0;
  }

  __syncthreads();
  float* redS = (float*)smem;
  float* redQ = (float*)(smem + 256);
  redS[wv * 64 + lane] = psum;
  redQ[wv * 64 + lane] = psq;
  __syncthreads();
  if (t < 64) {
    const float s = redS[t] + redS[64 + t] + redS[128 + t] + redS[192 + t];
    const float q = redQ[t] + redQ[64 + t] + redQ[128 + t] + redQ[192 + t];
    P2[t * SB + blockIdx.x] = s;
    P2[(64 + t) * SB + blockIdx.x] = q;
  }
}

// ------------------------------------------------- k_red2: T2 reduce + fin2
// Single block, same pattern as k_red1.

__global__ __launch_bounds__(256) void k_red2(
    const float* __restrict__ P2, const float* __restrict__ g2,
    const float* __restrict__ b2, float* __restrict__ params) {
  const int t = threadIdx.x;
  const int wave = t >> 6, lane = t & 63;
  __shared__ double T2d[128];
  for (int r = wave; r < 128; r += 4) {
    double sd = 0.0;
    for (int k = lane; k < SB; k += 64) sd += (double)P2[r * SB + k];
#pragma unroll
    for (int s = 1; s < 64; s <<= 1) sd += __shfl_xor(sd, s, 64);
    if (lane == 0) T2d[r] = sd;
  }
  __syncthreads();
  if (t < 64) {
    const double mean = T2d[t] / (double)NPTS;
    const double var = T2d[64 + t] / (double)NPTS - mean * mean;
    const double a = (double)g2[t] / sqrt(var + 0.001);
    params[128 + t] = (float)a;
    params[192 + t] = (float)((double)b2[t] - mean * a);
  }
}

// ------------------------------------------------- K5: final output pass (R20 exact)

__global__ __launch_bounds__(256) void k_final(
    const float* __restrict__ params, const float* __restrict__ Y2SEL,
    float* __restrict__ out) {
  const int idx = blockIdx.x * 256 + threadIdx.x;   // NPIL*64 total
  const int c = idx & 63;
  const float a2 = params[128 + c];
  const float b2 = params[192 + c];
  const float v = Y2SEL[idx];
  const float sel = (a2 >= 0.0f) ? v : -v;
  out[idx] = fmaxf(fmaf(sel, a2, b2), 0.0f);
}

// ---------------------------------------------------------------- launch

extern "C" void kernel_launch(void* const* d_in, const int* in_sizes, int n_in,
                              void* d_out, int out_size, void* d_ws, size_t ws_size,
                              hipStream_t stream) {
  const float4* vox = (const float4*)d_in[0];
  const int4* coords = (const int4*)d_in[1];
  const int* npnts = (const int*)d_in[2];
  const float* W1 = (const float*)d_in[3];
  const float* g1 = (const float*)d_in[4];
  const float* b1 = (const float*)d_in[5];
  const float* W2 = (const float*)d_in[6];
  const float* g2 = (const float*)d_in[7];
  const float* b2 = (const float*)d_in[8];
  float* out = (float*)d_out;

  char* w = (char*)d_ws;
  size_t off = 0;
  float* P1 = (float*)(w + off); off += (size_t)NMOM * K1_BLOCKS * 4;  // 324 KB
  float* P2 = (float*)(w + off); off += (size_t)128 * SB * 4;          // 524 KB
  float* params = (float*)(w + off); off += 256 * 4;                   // 256 f32
  float* Y2SEL = (float*)(w + off); off += (size_t)NPIL * 64 * 4;      // 12.3 MB

  k_moments<<<K1_BLOCKS, 256, 0, stream>>>(vox, coords, npnts, P1);
  k_red1<<<1, 256, 0, stream>>>(P1, W1, g1, b1, params);
  k_stats2<<<SB, 256, 0, stream>>>(vox, coords, npnts, W1, W2, g2, params, P2, Y2SEL);
  k_red2<<<1, 256, 0, stream>>>(P2, g2, b2, params);
  k_final<<<(NPIL * 64) / 256, 256, 0, stream>>>(params, Y2SEL, out);
}

// Round 24
// 153.269 us; speedup vs baseline: 3.6102x; 2.2544x over previous
//
#include <hip/hip_runtime.h>
#include <hip/hip_bf16.h>
#include <math.h>

#define NB 4
#define NPI 12000
#define NM 32
#define NPTS (NB*NPI*NM)      // 1536000
#define NPIL (NB*NPI)         // 48000

// k_moments config
#define K1_BLOCKS 1500
#define K1_STRIDE (K1_BLOCKS*256)   // 384000
#define K1_ITERS 4                  // NPTS / K1_STRIDE
#define NMOM 54                     // 9 Sf + 45 Sff

// heavy-kernel config
#define CHUNK 128
#define NBATCH (NPTS/CHUNK)   // 12000
#define SB 1024               // 4 blocks/CU x 256 CU resident (LDS 32KB)

typedef __attribute__((ext_vector_type(8))) short bfrag;     // 8 bf16 = 4 VGPRs
typedef __attribute__((ext_vector_type(16))) float f32x16;   // MFMA 32x32 acc

// ---------------------------------------------------------------- helpers

__device__ __forceinline__ void make_f(float4 v, int4 cc, int np, int m, float zc, float f[9]) {
  const float cx = ((float)cc.w + 0.5f) * 0.16f + 0.0f;
  const float cy = ((float)cc.z + 0.5f) * 0.16f - 39.68f;
  f[0] = v.x; f[1] = v.y; f[2] = v.z; f[3] = v.w;
  f[4] = v.x - cx; f[5] = v.y - cy; f[6] = cx; f[7] = cy; f[8] = zc;
  const float msk = (m < np) ? 1.0f : 0.0f;
#pragma unroll
  for (int i = 0; i < 9; ++i) f[i] *= msk;
}

// ------------------------------------------------- K1: f-moments (R20 exact)

__global__ __launch_bounds__(256) void k_moments(
    const float4* __restrict__ vox, const int4* __restrict__ coords,
    const int* __restrict__ npnts, float* __restrict__ P1) {
  const int t = blockIdx.x * 256 + threadIdx.x;
  float acc[NMOM];
#pragma unroll
  for (int v = 0; v < NMOM; ++v) acc[v] = 0.0f;

#pragma unroll
  for (int j = 0; j < K1_ITERS; ++j) {
    const int pt = t + j * K1_STRIDE;
    const int pil = pt >> 5;
    const int m = pt & 31;
    const float4 v = vox[pt];
    const int4 cc = coords[pil];
    const int np = npnts[pil];
    float z = v.z;
#pragma unroll
    for (int s = 1; s < 32; s <<= 1) z += __shfl_xor(z, s, 32);
    const float zc = z * (1.0f / 32.0f);
    float f[9];
    make_f(v, cc, np, m, zc, f);
    int vi = 0;
#pragma unroll
    for (int i = 0; i < 9; ++i) acc[vi++] += f[i];
#pragma unroll
    for (int i = 0; i < 9; ++i)
#pragma unroll
      for (int jj = i; jj < 9; ++jj) acc[vi++] += f[i] * f[jj];
  }

#pragma unroll
  for (int v = 0; v < NMOM; ++v) {
    float x = acc[v];
#pragma unroll
    for (int s = 1; s < 64; s <<= 1) x += __shfl_xor(x, s, 64);
    acc[v] = x;
  }
  __shared__ float red[4][NMOM];
  const int wave = threadIdx.x >> 6, lane = threadIdx.x & 63;
  if (lane == 0) {
#pragma unroll
    for (int v = 0; v < NMOM; ++v) red[wave][v] = acc[v];
  }
  __syncthreads();
  if (threadIdx.x < NMOM) {
    float s = red[0][threadIdx.x] + red[1][threadIdx.x] + red[2][threadIdx.x] + red[3][threadIdx.x];
    P1[threadIdx.x * K1_BLOCKS + blockIdx.x] = s;
  }
}

// ------------------------------------------------- k_red1: T1 reduce + fin1
// Single block. R23 post-mortem: the dependent-chain loads serialized at
// ~500cy each (no TLP to hide; 0.01% VALUBusy). Fix: batch loads into regs
// (all issue before any consume -> one round-trip per batch), then sum in
// the SAME ascending order (bit-identical).

__global__ __launch_bounds__(256) void k_red1(
    const float* __restrict__ P1, const float* __restrict__ W1,
    const float* __restrict__ g1, const float* __restrict__ b1,
    float* __restrict__ params) {
  const int t = threadIdx.x;
  const int wave = t >> 6, lane = t & 63;
  __shared__ double T1d[NMOM];
  for (int r = wave; r < NMOM; r += 4) {
    const float* row = P1 + r * K1_BLOCKS;
    double sd = 0.0;
    int k = lane;
    for (; k + 64 * 8 <= K1_BLOCKS; k += 64 * 8) {
      float vb[8];
#pragma unroll
      for (int j = 0; j < 8; ++j) vb[j] = row[k + 64 * j];   // loads batch-issue
#pragma unroll
      for (int j = 0; j < 8; ++j) sd += (double)vb[j];
    }
    for (; k < K1_BLOCKS; k += 64) sd += (double)row[k];
#pragma unroll
    for (int s = 1; s < 64; s <<= 1) sd += __shfl_xor(sd, s, 64);
    if (lane == 0) T1d[r] = sd;
  }
  __syncthreads();
  if (t < 64) {
    double w[9];
#pragma unroll
    for (int i = 0; i < 9; ++i) w[i] = (double)W1[i * 64 + t];
    double mean = 0.0;
#pragma unroll
    for (int i = 0; i < 9; ++i) mean += w[i] * T1d[i];
    mean /= (double)NPTS;
    double e2 = 0.0;
    int vi = 9;
#pragma unroll
    for (int i = 0; i < 9; ++i)
#pragma unroll
      for (int j = i; j < 9; ++j) {
        const double tt = T1d[vi++] * w[i] * w[j];
        e2 += (i == j) ? tt : 2.0 * tt;
      }
    e2 /= (double)NPTS;
    const double var = e2 - mean * mean;
    const double a = (double)g1[t] / sqrt(var + 0.001);
    params[t] = (float)a;
    params[64 + t] = (float)((double)b1[t] - mean * a);
  }
}

// ------------------------------------------------- K3: both layers via MFMA (R20 exact)

__global__ __launch_bounds__(256) void k_stats2(
    const float4* __restrict__ vox, const int4* __restrict__ coords,
    const int* __restrict__ npnts, const float* __restrict__ W1,
    const float* __restrict__ W2, const float* __restrict__ g2,
    const float* __restrict__ params, float* __restrict__ P2,
    float* __restrict__ Y2SEL) {
  __shared__ __align__(16) unsigned int smem[8192];   // 32768 B total
  unsigned short* h1 = (unsigned short*)smem;                // [128][64] u16 (swz)
  unsigned short* W2T = (unsigned short*)(smem + 4096);      // [64][128] u16 interleaved (swz)
  unsigned short* W1Thi = (unsigned short*)smem;             // [64][16] (init-only alias)
  unsigned short* W1Tlo = (unsigned short*)(smem + 512);     // [64][16]

  const int t = threadIdx.x;
  for (int i = t; i < 1024; i += 256) {
    const int c = i >> 4, k = i & 15;
    float x;
    if (k < 9)       x = W1[k * 64 + c] * params[c];
    else if (k == 9) x = params[64 + c];
    else             x = 0.0f;
    const unsigned int b = __float_as_uint(x);
    W1Thi[c * 16 + k] = (unsigned short)(b >> 16);
    const float r = x - __uint_as_float(b & 0xFFFF0000u);
    W1Tlo[c * 16 + k] = (unsigned short)(__float_as_uint(r) >> 16);
  }
  for (int i = t; i < 4096; i += 256) {
    const int k = i >> 6, c = i & 63;
    const float x = W2[i];
    const unsigned int b = __float_as_uint(x);
    const float r = x - __uint_as_float(b & 0xFFFF0000u);
    const int sw = (c & 15) << 3;
    W2T[c * 128 + (k ^ sw)] = (unsigned short)(b >> 16);
    W2T[c * 128 + ((64 + k) ^ sw)] = (unsigned short)(__float_as_uint(r) >> 16);
  }

  const int lane = t & 63;
  const int wv = t >> 6;
  const int ch = lane & 31;
  const float sg0 = (g2[ch] >= 0.0f) ? 1.0f : -1.0f;
  const float sg1 = (g2[32 + ch] >= 0.0f) ? 1.0f : -1.0f;
  __syncthreads();

  const int koff = 8 * (lane >> 5);
  const int arow = 32 * wv + ch;
  const int swB = (ch & 15) << 3;
  const int swA = (arow & 7) << 3;
  const bfrag w1h0 = *(const bfrag*)&W1Thi[ch * 16 + koff];
  const bfrag w1l0 = *(const bfrag*)&W1Tlo[ch * 16 + koff];
  const bfrag w1h1 = *(const bfrag*)&W1Thi[(32 + ch) * 16 + koff];
  const bfrag w1l1 = *(const bfrag*)&W1Tlo[(32 + ch) * 16 + koff];
  __syncthreads();

  f32x16 zero16;
#pragma unroll
  for (int i = 0; i < 16; ++i) zero16[i] = 0.0f;

  float psum = 0.0f, psq = 0.0f;

  int bb0 = blockIdx.x;
  float4 v = vox[bb0 * CHUNK + 32 * wv + ch];
  int4 cc = coords[bb0 * 4 + wv];
  int np = npnts[bb0 * 4 + wv];

  for (int bb = bb0; bb < NBATCH; bb += SB) {
    float z = v.z;
#pragma unroll
    for (int s = 1; s < 64; s <<= 1) z += __shfl_xor(z, s, 64);
    const float zc = z * (1.0f / 64.0f);
    float f[9];
    make_f(v, cc, np, ch, zc, f);
    {
      const int bbn = bb + SB;
      const int bbs = (bbn < NBATCH) ? bbn : bb;
      v = vox[bbs * CHUNK + 32 * wv + ch];
      cc = coords[bbs * 4 + wv];
      np = npnts[bbs * 4 + wv];
    }
    bfrag fa_hi, fa_lo;
    {
      unsigned int ahw[4] = {0u, 0u, 0u, 0u}, alw[4] = {0u, 0u, 0u, 0u};
#pragma unroll
      for (int e = 0; e < 8; ++e) {
        const float x = (lane < 32) ? f[e]
                        : ((e == 0) ? f[8] : (e == 1) ? 1.0f : 0.0f);
        const unsigned int b = __float_as_uint(x);
        const float r = x - __uint_as_float(b & 0xFFFF0000u);
        ahw[e >> 1] |= (b >> 16) << ((e & 1) * 16);
        alw[e >> 1] |= (__float_as_uint(r) >> 16) << ((e & 1) * 16);
      }
      union U { unsigned int u[4]; bfrag b; };
      U ch_, cl_;
      ch_.u[0] = ahw[0]; ch_.u[1] = ahw[1]; ch_.u[2] = ahw[2]; ch_.u[3] = ahw[3];
      cl_.u[0] = alw[0]; cl_.u[1] = alw[1]; cl_.u[2] = alw[2]; cl_.u[3] = alw[3];
      fa_hi = ch_.b; fa_lo = cl_.b;
    }

    f32x16 yA0 = __builtin_amdgcn_mfma_f32_32x32x16_bf16(fa_hi, w1h0, zero16, 0, 0, 0);
    f32x16 yA1 = __builtin_amdgcn_mfma_f32_32x32x16_bf16(fa_hi, w1h1, zero16, 0, 0, 0);
    yA0 = __builtin_amdgcn_mfma_f32_32x32x16_bf16(fa_hi, w1l0, yA0, 0, 0, 0);
    yA1 = __builtin_amdgcn_mfma_f32_32x32x16_bf16(fa_hi, w1l1, yA1, 0, 0, 0);
    yA0 = __builtin_amdgcn_mfma_f32_32x32x16_bf16(fa_lo, w1h0, yA0, 0, 0, 0);
    yA1 = __builtin_amdgcn_mfma_f32_32x32x16_bf16(fa_lo, w1h1, yA1, 0, 0, 0);

    const int rbase = 4 * (lane >> 5);
#pragma unroll
    for (int j = 0; j < 4; ++j) {
      const int swzj = ((j + rbase) & 7) << 3;
      unsigned short* bp0 = &h1[(32 * wv + rbase + j) * 64 + (ch ^ swzj)];
      unsigned short* bp1 = &h1[(32 * wv + rbase + j) * 64 + ((32 + ch) ^ swzj)];
#pragma unroll
      for (int q = 0; q < 4; ++q) {
        const int reg = j + 4 * q;
        {
          const __hip_bfloat16 hb = __float2bfloat16(fmaxf(yA0[reg], 0.0f));
          bp0[q * 512] = *(const unsigned short*)&hb;
        }
        {
          const __hip_bfloat16 hb = __float2bfloat16(fmaxf(yA1[reg], 0.0f));
          bp1[q * 512] = *(const unsigned short*)&hb;
        }
      }
    }
    // no barrier: wave-private rows (within-wave DS ordering)

    f32x16 acc0, acc1;
#pragma unroll
    for (int ks = 0; ks < 4; ++ks) {
      const int kk = koff + 16 * ks;
      const bfrag ahi = *(const bfrag*)&h1[arow * 64 + (kk ^ swA)];
      const bfrag bhi0 = *(const bfrag*)&W2T[ch * 128 + (kk ^ swB)];
      const bfrag blo0 = *(const bfrag*)&W2T[ch * 128 + ((64 + kk) ^ swB)];
      const bfrag bhi1 = *(const bfrag*)&W2T[(32 + ch) * 128 + (kk ^ swB)];
      const bfrag blo1 = *(const bfrag*)&W2T[(32 + ch) * 128 + ((64 + kk) ^ swB)];
      if (ks == 0) {
        acc0 = __builtin_amdgcn_mfma_f32_32x32x16_bf16(ahi, bhi0, zero16, 0, 0, 0);
        acc1 = __builtin_amdgcn_mfma_f32_32x32x16_bf16(ahi, bhi1, zero16, 0, 0, 0);
      } else {
        acc0 = __builtin_amdgcn_mfma_f32_32x32x16_bf16(ahi, bhi0, acc0, 0, 0, 0);
        acc1 = __builtin_amdgcn_mfma_f32_32x32x16_bf16(ahi, bhi1, acc1, 0, 0, 0);
      }
      acc0 = __builtin_amdgcn_mfma_f32_32x32x16_bf16(ahi, blo0, acc0, 0, 0, 0);
      acc1 = __builtin_amdgcn_mfma_f32_32x32x16_bf16(ahi, blo1, acc1, 0, 0, 0);
    }

    float s0 = 0, q0 = 0, m0 = -INFINITY, s1 = 0, q1 = 0, m1 = -INFINITY;
#pragma unroll
    for (int i = 0; i < 16; ++i) {
      const float v0 = acc0[i], v1 = acc1[i];
      s0 += v0; q0 = fmaf(v0, v0, q0); m0 = fmaxf(m0, v0 * sg0);
      s1 += v1; q1 = fmaf(v1, v1, q1); m1 = fmaxf(m1, v1 * sg1);
    }
    s0 += __shfl_xor(s0, 32, 64); q0 += __shfl_xor(q0, 32, 64);
    m0 = fmaxf(m0, __shfl_xor(m0, 32, 64));
    s1 += __shfl_xor(s1, 32, 64); q1 += __shfl_xor(q1, 32, 64);
    m1 = fmaxf(m1, __shfl_xor(m1, 32, 64));
    const bool hiHalf = lane >= 32;
    psum += hiHalf ? s1 : s0;
    psq += hiHalf ? q1 : q0;
    Y2SEL[(bb * 4 + wv) * 64 + lane] = hiHalf ? m1 : m0;
  }

  __syncthreads();
  float* redS = (float*)smem;
  float* redQ = (float*)(smem + 256);
  redS[wv * 64 + lane] = psum;
  redQ[wv * 64 + lane] = psq;
  __syncthreads();
  if (t < 64) {
    const float s = redS[t] + redS[64 + t] + redS[128 + t] + redS[192 + t];
    const float q = redQ[t] + redQ[64 + t] + redQ[128 + t] + redQ[192 + t];
    P2[t * SB + blockIdx.x] = s;
    P2[(64 + t) * SB + blockIdx.x] = q;
  }
}

// ------------------------------------------------- k_red2: T2 reduce + fin2
// Single block, ILP-batched loads (16 per row, one round-trip).

__global__ __launch_bounds__(256) void k_red2(
    const float* __restrict__ P2, const float* __restrict__ g2,
    const float* __restrict__ b2, float* __restrict__ params) {
  const int t = threadIdx.x;
  const int wave = t >> 6, lane = t & 63;
  __shared__ double T2d[128];
  for (int r = wave; r < 128; r += 4) {
    const float* row = P2 + r * SB;
    float vb[16];
#pragma unroll
    for (int j = 0; j < 16; ++j) vb[j] = row[lane + 64 * j];   // batch-issue
    double sd = 0.0;
#pragma unroll
    for (int j = 0; j < 16; ++j) sd += (double)vb[j];
#pragma unroll
    for (int s = 1; s < 64; s <<= 1) sd += __shfl_xor(sd, s, 64);
    if (lane == 0) T2d[r] = sd;
  }
  __syncthreads();
  if (t < 64) {
    const double mean = T2d[t] / (double)NPTS;
    const double var = T2d[64 + t] / (double)NPTS - mean * mean;
    const double a = (double)g2[t] / sqrt(var + 0.001);
    params[128 + t] = (float)a;
    params[192 + t] = (float)((double)b2[t] - mean * a);
  }
}

// ------------------------------------------------- K5: final output pass (R20 exact)

__global__ __launch_bounds__(256) void k_final(
    const float* __restrict__ params, const float* __restrict__ Y2SEL,
    float* __restrict__ out) {
  const int idx = blockIdx.x * 256 + threadIdx.x;   // NPIL*64 total
  const int c = idx & 63;
  const float a2 = params[128 + c];
  const float b2 = params[192 + c];
  const float v = Y2SEL[idx];
  const float sel = (a2 >= 0.0f) ? v : -v;
  out[idx] = fmaxf(fmaf(sel, a2, b2), 0.0f);
}

// ---------------------------------------------------------------- launch

extern "C" void kernel_launch(void* const* d_in, const int* in_sizes, int n_in,
                              void* d_out, int out_size, void* d_ws, size_t ws_size,
                              hipStream_t stream) {
  const float4* vox = (const float4*)d_in[0];
  const int4* coords = (const int4*)d_in[1];
  const int* npnts = (const int*)d_in[2];
  const float* W1 = (const float*)d_in[3];
  const float* g1 = (const float*)d_in[4];
  const float* b1 = (const float*)d_in[5];
  const float* W2 = (const float*)d_in[6];
  const float* g2 = (const float*)d_in[7];
  const float* b2 = (const float*)d_in[8];
  float* out = (float*)d_out;

  char* w = (char*)d_ws;
  size_t off = 0;
  float* P1 = (float*)(w + off); off += (size_t)NMOM * K1_BLOCKS * 4;  // 324 KB
  float* P2 = (float*)(w + off); off += (size_t)128 * SB * 4;          // 524 KB
  float* params = (float*)(w + off); off += 256 * 4;                   // 256 f32
  float* Y2SEL = (float*)(w + off); off += (size_t)NPIL * 64 * 4;      // 12.3 MB

  k_moments<<<K1_BLOCKS, 256, 0, stream>>>(vox, coords, npnts, P1);
  k_red1<<<1, 256, 0, stream>>>(P1, W1, g1, b1, params);
  k_stats2<<<SB, 256, 0, stream>>>(vox, coords, npnts, W1, W2, g2, params, P2, Y2SEL);
  k_red2<<<1, 256, 0, stream>>>(P2, g2, b2, params);
  k_final<<<(NPIL * 64) / 256, 256, 0, stream>>>(params, Y2SEL, out);
}

// Round 25
// 97.081 us; speedup vs baseline: 5.6997x; 1.5788x over previous
//
#include <hip/hip_runtime.h>
#include <hip/hip_bf16.h>
#include <math.h>

#define NB 4
#define NPI 12000
#define NM 32
#define NPTS (NB*NPI*NM)      // 1536000
#define NPIL (NB*NPI)         // 48000

// k_moments config
#define K1_BLOCKS 1500
#define K1_STRIDE (K1_BLOCKS*256)   // 384000
#define K1_ITERS 4                  // NPTS / K1_STRIDE
#define NMOM 54                     // 9 Sf + 45 Sff

// heavy-kernel config
#define CHUNK 128
#define NBATCH (NPTS/CHUNK)   // 12000
#define SB 1024               // 4 blocks/CU x 256 CU resident (LDS 32KB)

typedef __attribute__((ext_vector_type(8))) short bfrag;     // 8 bf16 = 4 VGPRs
typedef __attribute__((ext_vector_type(16))) float f32x16;   // MFMA 32x32 acc

// ---------------------------------------------------------------- helpers

__device__ __forceinline__ void make_f(float4 v, int4 cc, int np, int m, float zc, float f[9]) {
  const float cx = ((float)cc.w + 0.5f) * 0.16f + 0.0f;
  const float cy = ((float)cc.z + 0.5f) * 0.16f - 39.68f;
  f[0] = v.x; f[1] = v.y; f[2] = v.z; f[3] = v.w;
  f[4] = v.x - cx; f[5] = v.y - cy; f[6] = cx; f[7] = cy; f[8] = zc;
  const float msk = (m < np) ? 1.0f : 0.0f;
#pragma unroll
  for (int i = 0; i < 9; ++i) f[i] *= msk;
}

// ------------------------------------------------- K1: f-moments (R20 exact)

__global__ __launch_bounds__(256) void k_moments(
    const float4* __restrict__ vox, const int4* __restrict__ coords,
    const int* __restrict__ npnts, float* __restrict__ P1) {
  const int t = blockIdx.x * 256 + threadIdx.x;
  float acc[NMOM];
#pragma unroll
  for (int v = 0; v < NMOM; ++v) acc[v] = 0.0f;

#pragma unroll
  for (int j = 0; j < K1_ITERS; ++j) {
    const int pt = t + j * K1_STRIDE;
    const int pil = pt >> 5;
    const int m = pt & 31;
    const float4 v = vox[pt];
    const int4 cc = coords[pil];
    const int np = npnts[pil];
    float z = v.z;
#pragma unroll
    for (int s = 1; s < 32; s <<= 1) z += __shfl_xor(z, s, 32);
    const float zc = z * (1.0f / 32.0f);
    float f[9];
    make_f(v, cc, np, m, zc, f);
    int vi = 0;
#pragma unroll
    for (int i = 0; i < 9; ++i) acc[vi++] += f[i];
#pragma unroll
    for (int i = 0; i < 9; ++i)
#pragma unroll
      for (int jj = i; jj < 9; ++jj) acc[vi++] += f[i] * f[jj];
  }

#pragma unroll
  for (int v = 0; v < NMOM; ++v) {
    float x = acc[v];
#pragma unroll
    for (int s = 1; s < 64; s <<= 1) x += __shfl_xor(x, s, 64);
    acc[v] = x;
  }
  __shared__ float red[4][NMOM];
  const int wave = threadIdx.x >> 6, lane = threadIdx.x & 63;
  if (lane == 0) {
#pragma unroll
    for (int v = 0; v < NMOM; ++v) red[wave][v] = acc[v];
  }
  __syncthreads();
  if (threadIdx.x < NMOM) {
    float s = red[0][threadIdx.x] + red[1][threadIdx.x] + red[2][threadIdx.x] + red[3][threadIdx.x];
    P1[threadIdx.x * K1_BLOCKS + blockIdx.x] = s;
  }
}

// ------------------------------------------------- generic row reduce (f32 -> f64)
// R20 exact: one block per row, coalesced reads, full TLP across rows.
// (R23/R24 lesson: single-block reductions are latency-poor -- keep this.)

__global__ __launch_bounds__(256) void k_rowreduce(
    const float* __restrict__ src, double* __restrict__ dst, int ncols) {
  const int row = blockIdx.x;
  const float* p = src + row * ncols;
  double sd = 0.0;
  for (int i = threadIdx.x; i < ncols; i += 256) sd += (double)p[i];
#pragma unroll
  for (int s = 1; s < 64; s <<= 1) sd += __shfl_xor(sd, s, 64);
  __shared__ double rd[4];
  const int wave = threadIdx.x >> 6, lane = threadIdx.x & 63;
  if (lane == 0) rd[wave] = sd;
  __syncthreads();
  if (threadIdx.x == 0) dst[row] = rd[0] + rd[1] + rd[2] + rd[3];
}

// ------------------------------------------------- K3: both layers via MFMA
// R20 body exact; prologue change only: fin1 computed INLINE from T1d
// (64 threads, f64, barrier-separated from the hot loop) -- eliminates the
// k_fin1 launch. a1s/b1s live in the init-only LDS alias region.

__global__ __launch_bounds__(256) void k_stats2(
    const float4* __restrict__ vox, const int4* __restrict__ coords,
    const int* __restrict__ npnts, const float* __restrict__ W1,
    const float* __restrict__ W2, const float* __restrict__ g1,
    const float* __restrict__ b1, const float* __restrict__ g2,
    const double* __restrict__ T1d, float* __restrict__ P2,
    float* __restrict__ Y2SEL) {
  __shared__ __align__(16) unsigned int smem[8192];   // 32768 B total
  unsigned short* h1 = (unsigned short*)smem;                // [128][64] u16 (swz)
  unsigned short* W2T = (unsigned short*)(smem + 4096);      // [64][128] u16 interleaved (swz)
  unsigned short* W1Thi = (unsigned short*)smem;             // [64][16] (init-only alias)
  unsigned short* W1Tlo = (unsigned short*)(smem + 512);     // [64][16]
  float* a1s = (float*)(smem + 1024);                        // [64] (init-only alias)
  float* b1s = (float*)(smem + 1088);                        // [64]

  const int t = threadIdx.x;
  // ---- inline fin1 (was k_fin1): 64 threads, f64, identical math/order
  if (t < 64) {
    double w[9];
#pragma unroll
    for (int i = 0; i < 9; ++i) w[i] = (double)W1[i * 64 + t];
    double mean = 0.0;
#pragma unroll
    for (int i = 0; i < 9; ++i) mean += w[i] * T1d[i];
    mean /= (double)NPTS;
    double e2 = 0.0;
    int vi = 9;
#pragma unroll
    for (int i = 0; i < 9; ++i)
#pragma unroll
      for (int j = i; j < 9; ++j) {
        const double tt = T1d[vi++] * w[i] * w[j];
        e2 += (i == j) ? tt : 2.0 * tt;
      }
    e2 /= (double)NPTS;
    const double var = e2 - mean * mean;
    const double a = (double)g1[t] / sqrt(var + 0.001);
    a1s[t] = (float)a;
    b1s[t] = (float)((double)b1[t] - mean * a);
  }
  __syncthreads();

  // ---- stage W1aug^T split (k<9: W1*a1; k==9: b1adj; pad to 16)
  for (int i = t; i < 1024; i += 256) {
    const int c = i >> 4, k = i & 15;
    float x;
    if (k < 9)       x = W1[k * 64 + c] * a1s[c];
    else if (k == 9) x = b1s[c];
    else             x = 0.0f;
    const unsigned int b = __float_as_uint(x);
    W1Thi[c * 16 + k] = (unsigned short)(b >> 16);
    const float r = x - __uint_as_float(b & 0xFFFF0000u);
    W1Tlo[c * 16 + k] = (unsigned short)(__float_as_uint(r) >> 16);
  }
  // ---- stage W2^T split, interleaved+swizzled
  for (int i = t; i < 4096; i += 256) {
    const int k = i >> 6, c = i & 63;
    const float x = W2[i];
    const unsigned int b = __float_as_uint(x);
    const float r = x - __uint_as_float(b & 0xFFFF0000u);
    const int sw = (c & 15) << 3;
    W2T[c * 128 + (k ^ sw)] = (unsigned short)(b >> 16);
    W2T[c * 128 + ((64 + k) ^ sw)] = (unsigned short)(__float_as_uint(r) >> 16);
  }

  const int lane = t & 63;
  const int wv = t >> 6;
  const int ch = lane & 31;
  const float sg0 = (g2[ch] >= 0.0f) ? 1.0f : -1.0f;
  const float sg1 = (g2[32 + ch] >= 0.0f) ? 1.0f : -1.0f;
  __syncthreads();

  const int koff = 8 * (lane >> 5);
  const int arow = 32 * wv + ch;
  const int swB = (ch & 15) << 3;
  const int swA = (arow & 7) << 3;
  const bfrag w1h0 = *(const bfrag*)&W1Thi[ch * 16 + koff];
  const bfrag w1l0 = *(const bfrag*)&W1Tlo[ch * 16 + koff];
  const bfrag w1h1 = *(const bfrag*)&W1Thi[(32 + ch) * 16 + koff];
  const bfrag w1l1 = *(const bfrag*)&W1Tlo[(32 + ch) * 16 + koff];
  __syncthreads();

  f32x16 zero16;
#pragma unroll
  for (int i = 0; i < 16; ++i) zero16[i] = 0.0f;

  float psum = 0.0f, psq = 0.0f;

  int bb0 = blockIdx.x;
  float4 v = vox[bb0 * CHUNK + 32 * wv + ch];
  int4 cc = coords[bb0 * 4 + wv];
  int np = npnts[bb0 * 4 + wv];

  for (int bb = bb0; bb < NBATCH; bb += SB) {
    float z = v.z;
#pragma unroll
    for (int s = 1; s < 64; s <<= 1) z += __shfl_xor(z, s, 64);
    const float zc = z * (1.0f / 64.0f);
    float f[9];
    make_f(v, cc, np, ch, zc, f);
    {
      const int bbn = bb + SB;
      const int bbs = (bbn < NBATCH) ? bbn : bb;
      v = vox[bbs * CHUNK + 32 * wv + ch];
      cc = coords[bbs * 4 + wv];
      np = npnts[bbs * 4 + wv];
    }
    bfrag fa_hi, fa_lo;
    {
      unsigned int ahw[4] = {0u, 0u, 0u, 0u}, alw[4] = {0u, 0u, 0u, 0u};
#pragma unroll
      for (int e = 0; e < 8; ++e) {
        const float x = (lane < 32) ? f[e]
                        : ((e == 0) ? f[8] : (e == 1) ? 1.0f : 0.0f);
        const unsigned int b = __float_as_uint(x);
        const float r = x - __uint_as_float(b & 0xFFFF0000u);
        ahw[e >> 1] |= (b >> 16) << ((e & 1) * 16);
        alw[e >> 1] |= (__float_as_uint(r) >> 16) << ((e & 1) * 16);
      }
      union U { unsigned int u[4]; bfrag b; };
      U ch_, cl_;
      ch_.u[0] = ahw[0]; ch_.u[1] = ahw[1]; ch_.u[2] = ahw[2]; ch_.u[3] = ahw[3];
      cl_.u[0] = alw[0]; cl_.u[1] = alw[1]; cl_.u[2] = alw[2]; cl_.u[3] = alw[3];
      fa_hi = ch_.b; fa_lo = cl_.b;
    }

    f32x16 yA0 = __builtin_amdgcn_mfma_f32_32x32x16_bf16(fa_hi, w1h0, zero16, 0, 0, 0);
    f32x16 yA1 = __builtin_amdgcn_mfma_f32_32x32x16_bf16(fa_hi, w1h1, zero16, 0, 0, 0);
    yA0 = __builtin_amdgcn_mfma_f32_32x32x16_bf16(fa_hi, w1l0, yA0, 0, 0, 0);
    yA1 = __builtin_amdgcn_mfma_f32_32x32x16_bf16(fa_hi, w1l1, yA1, 0, 0, 0);
    yA0 = __builtin_amdgcn_mfma_f32_32x32x16_bf16(fa_lo, w1h0, yA0, 0, 0, 0);
    yA1 = __builtin_amdgcn_mfma_f32_32x32x16_bf16(fa_lo, w1h1, yA1, 0, 0, 0);

    const int rbase = 4 * (lane >> 5);
#pragma unroll
    for (int j = 0; j < 4; ++j) {
      const int swzj = ((j + rbase) & 7) << 3;
      unsigned short* bp0 = &h1[(32 * wv + rbase + j) * 64 + (ch ^ swzj)];
      unsigned short* bp1 = &h1[(32 * wv + rbase + j) * 64 + ((32 + ch) ^ swzj)];
#pragma unroll
      for (int q = 0; q < 4; ++q) {
        const int reg = j + 4 * q;
        {
          const __hip_bfloat16 hb = __float2bfloat16(fmaxf(yA0[reg], 0.0f));
          bp0[q * 512] = *(const unsigned short*)&hb;
        }
        {
          const __hip_bfloat16 hb = __float2bfloat16(fmaxf(yA1[reg], 0.0f));
          bp1[q * 512] = *(const unsigned short*)&hb;
        }
      }
    }
    // no barrier: wave-private rows (within-wave DS ordering)

    f32x16 acc0, acc1;
#pragma unroll
    for (int ks = 0; ks < 4; ++ks) {
      const int kk = koff + 16 * ks;
      const bfrag ahi = *(const bfrag*)&h1[arow * 64 + (kk ^ swA)];
      const bfrag bhi0 = *(const bfrag*)&W2T[ch * 128 + (kk ^ swB)];
      const bfrag blo0 = *(const bfrag*)&W2T[ch * 128 + ((64 + kk) ^ swB)];
      const bfrag bhi1 = *(const bfrag*)&W2T[(32 + ch) * 128 + (kk ^ swB)];
      const bfrag blo1 = *(const bfrag*)&W2T[(32 + ch) * 128 + ((64 + kk) ^ swB)];
      if (ks == 0) {
        acc0 = __builtin_amdgcn_mfma_f32_32x32x16_bf16(ahi, bhi0, zero16, 0, 0, 0);
        acc1 = __builtin_amdgcn_mfma_f32_32x32x16_bf16(ahi, bhi1, zero16, 0, 0, 0);
      } else {
        acc0 = __builtin_amdgcn_mfma_f32_32x32x16_bf16(ahi, bhi0, acc0, 0, 0, 0);
        acc1 = __builtin_amdgcn_mfma_f32_32x32x16_bf16(ahi, bhi1, acc1, 0, 0, 0);
      }
      acc0 = __builtin_amdgcn_mfma_f32_32x32x16_bf16(ahi, blo0, acc0, 0, 0, 0);
      acc1 = __builtin_amdgcn_mfma_f32_32x32x16_bf16(ahi, blo1, acc1, 0, 0, 0);
    }

    float s0 = 0, q0 = 0, m0 = -INFINITY, s1 = 0, q1 = 0, m1 = -INFINITY;
#pragma unroll
    for (int i = 0; i < 16; ++i) {
      const float v0 = acc0[i], v1 = acc1[i];
      s0 += v0; q0 = fmaf(v0, v0, q0); m0 = fmaxf(m0, v0 * sg0);
      s1 += v1; q1 = fmaf(v1, v1, q1); m1 = fmaxf(m1, v1 * sg1);
    }
    s0 += __shfl_xor(s0, 32, 64); q0 += __shfl_xor(q0, 32, 64);
    m0 = fmaxf(m0, __shfl_xor(m0, 32, 64));
    s1 += __shfl_xor(s1, 32, 64); q1 += __shfl_xor(q1, 32, 64);
    m1 = fmaxf(m1, __shfl_xor(m1, 32, 64));
    const bool hiHalf = lane >= 32;
    psum += hiHalf ? s1 : s0;
    psq += hiHalf ? q1 : q0;
    Y2SEL[(bb * 4 + wv) * 64 + lane] = hiHalf ? m1 : m0;
  }

  __syncthreads();
  float* redS = (float*)smem;
  float* redQ = (float*)(smem + 256);
  redS[wv * 64 + lane] = psum;
  redQ[wv * 64 + lane] = psq;
  __syncthreads();
  if (t < 64) {
    const float s = redS[t] + redS[64 + t] + redS[128 + t] + redS[192 + t];
    const float q = redQ[t] + redQ[64 + t] + redQ[128 + t] + redQ[192 + t];
    P2[t * SB + blockIdx.x] = s;
    P2[(64 + t) * SB + blockIdx.x] = q;
  }
}

// ------------------------------------------------- K5: final output pass
// R20 body; prologue computes fin2 INLINE from T2d (2 broadcast f64 loads
// per thread, L2-hot) -- eliminates the k_fin2 launch.

__global__ __launch_bounds__(256) void k_final(
    const double* __restrict__ T2d, const float* __restrict__ g2,
    const float* __restrict__ b2, const float* __restrict__ Y2SEL,
    float* __restrict__ out) {
  __shared__ float a2s[64], b2s[64];
  const int t = threadIdx.x;
  if (t < 64) {
    const double mean = T2d[t] / (double)NPTS;
    const double var = T2d[64 + t] / (double)NPTS - mean * mean;
    const double a = (double)g2[t] / sqrt(var + 0.001);
    a2s[t] = (float)a;
    b2s[t] = (float)((double)b2[t] - mean * a);
  }
  __syncthreads();
  const int idx = blockIdx.x * 256 + t;   // NPIL*64 total
  const int c = idx & 63;
  const float a2 = a2s[c];
  const float b2v = b2s[c];
  const float v = Y2SEL[idx];
  const float sel = (a2 >= 0.0f) ? v : -v;
  out[idx] = fmaxf(fmaf(sel, a2, b2v), 0.0f);
}

// ---------------------------------------------------------------- launch

extern "C" void kernel_launch(void* const* d_in, const int* in_sizes, int n_in,
                              void* d_out, int out_size, void* d_ws, size_t ws_size,
                              hipStream_t stream) {
  const float4* vox = (const float4*)d_in[0];
  const int4* coords = (const int4*)d_in[1];
  const int* npnts = (const int*)d_in[2];
  const float* W1 = (const float*)d_in[3];
  const float* g1 = (const float*)d_in[4];
  const float* b1 = (const float*)d_in[5];
  const float* W2 = (const float*)d_in[6];
  const float* g2 = (const float*)d_in[7];
  const float* b2 = (const float*)d_in[8];
  float* out = (float*)d_out;

  char* w = (char*)d_ws;
  size_t off = 0;
  double* T1 = (double*)(w + off); off += 512;                         // 54 f64
  double* T2 = (double*)(w + off); off += 1024;                        // 128 f64
  float* P1 = (float*)(w + off); off += (size_t)NMOM * K1_BLOCKS * 4;  // 324 KB
  float* P2 = (float*)(w + off); off += (size_t)128 * SB * 4;          // 524 KB
  float* Y2SEL = (float*)(w + off); off += (size_t)NPIL * 64 * 4;      // 12.3 MB

  k_moments<<<K1_BLOCKS, 256, 0, stream>>>(vox, coords, npnts, P1);
  k_rowreduce<<<NMOM, 256, 0, stream>>>(P1, T1, K1_BLOCKS);
  k_stats2<<<SB, 256, 0, stream>>>(vox, coords, npnts, W1, W2, g1, b1, g2,
                                   T1, P2, Y2SEL);
  k_rowreduce<<<128, 256, 0, stream>>>(P2, T2, SB);
  k_final<<<(NPIL * 64) / 256, 256, 0, stream>>>(T2, g2, b2, Y2SEL, out);
}